// Round 3
// baseline (862.894 us; speedup 1.0000x reference)
//
#include <hip/hip_runtime.h>

// FootprintExtruder: extrude [H,W] height/seg maps into [Z,H,W] int32 volume.
// Reference constants (L1_HEIGHT=0 makes the z<L1_HEIGHT branch dead):
#define ROOF_HEIGHT 1
#define ROOF_ID_OFFSET 1
#define FP_ID_MIN 100
#define FP_ID_MAX 5000
#define MAX_HEIGHT 384
#define HH 768
#define WW 768
#define HW (HH * WW)     // 589824, divisible by 1024
#define ZPB 16           // z-planes per block: 384/16 = 24 y-blocks

typedef int vint4 __attribute__((ext_vector_type(4)));

// Per-column semantics (hf = height, s = seg):
//   z <  hf-1 -> s
//   z == hf-1 -> s+1 if 100 <= s < 5000 else s   (roof voxel)
//   z >= hf   -> 0
__global__ __launch_bounds__(256) void extrude_kernel(
        const int* __restrict__ hf_map, const int* __restrict__ seg_map,
        int* __restrict__ out) {
    const int p  = (blockIdx.x * 256 + threadIdx.x) * 4;  // plane offset
    const int z0 = blockIdx.y * ZPB;

    const vint4 hf4 = *(const vint4*)(hf_map  + p);
    const vint4 sg4 = *(const vint4*)(seg_map + p);

    // Roof value for z == hf-1: seg + (is_footprint ? 1 : 0)
    vint4 roof;
    roof.x = sg4.x + ((sg4.x >= FP_ID_MIN) & (sg4.x < FP_ID_MAX));
    roof.y = sg4.y + ((sg4.y >= FP_ID_MIN) & (sg4.y < FP_ID_MAX));
    roof.z = sg4.z + ((sg4.z >= FP_ID_MIN) & (sg4.z < FP_ID_MAX));
    roof.w = sg4.w + ((sg4.w >= FP_ID_MIN) & (sg4.w < FP_ID_MAX));

    int* outp = out + (size_t)z0 * HW + p;
    #pragma unroll
    for (int i = 0; i < ZPB; ++i) {
        const int z = z0 + i;
        vint4 o;
        o.x = (z < hf4.x - 1) ? sg4.x : ((z == hf4.x - 1) ? roof.x : 0);
        o.y = (z < hf4.y - 1) ? sg4.y : ((z == hf4.y - 1) ? roof.y : 0);
        o.z = (z < hf4.z - 1) ? sg4.z : ((z == hf4.z - 1) ? roof.z : 0);
        o.w = (z < hf4.w - 1) ? sg4.w : ((z == hf4.w - 1) ? roof.w : 0);
        // Plain (cached) store — NT store measured 6x slower than the
        // fillBuffer store path on gfx950 (R2: 1.08 TB/s vs 6.3 TB/s).
        *(vint4*)outp = o;
        outp += HW;
    }
}

extern "C" void kernel_launch(void* const* d_in, const int* in_sizes, int n_in,
                              void* d_out, int out_size, void* d_ws, size_t ws_size,
                              hipStream_t stream) {
    const int* hf  = (const int*)d_in[0];   // height_field [1,768,768] int32
    const int* seg = (const int*)d_in[1];   // seg_map      [1,768,768] int32
    int* out = (int*)d_out;                 // [1,384,768,768] int32

    dim3 grid(HW / 1024, MAX_HEIGHT / ZPB); // 576 x 24 blocks
    extrude_kernel<<<grid, 256, 0, stream>>>(hf, seg, out);
}